// Round 14
// baseline (225.173 us; speedup 1.0000x reference)
//
#include <hip/hip_runtime.h>

typedef __bf16 bf16;
typedef __attribute__((ext_vector_type(8))) __bf16 bf16x8;
typedef __attribute__((ext_vector_type(4))) float f32x4;
typedef __attribute__((ext_vector_type(4))) unsigned int u32x4;

#define DINC 256
#define HIDC 512
#define XLRW 768   // xlry row width: [xl(256) | xr(256) | y(256)]
#define NSH  4     // shards (by edge & 3)
#define NB   256   // buckets of 32 nodes (node >> 5)

__device__ __forceinline__ float lrelu02(float v) { return fmaxf(v, 0.2f * v); }

__device__ __forceinline__ void gload_lds16(const void* g, void* l) {
    __builtin_amdgcn_global_load_lds(
        (const __attribute__((address_space(1))) unsigned int*)g,
        (__attribute__((address_space(3))) unsigned int*)l, 16, 0, 0);
}

// ---------------------------------------------------------------------------
// 64x64 tile BK=64 bf16 MFMA GEMM body, bank-conflict-free via XOR swizzle.
// ---------------------------------------------------------------------------
__device__ __forceinline__ void gemm64_body(
    const bf16* __restrict__ A, const bf16* __restrict__ Bt,
    const float* __restrict__ bias, void* __restrict__ Cout,
    int K, int ldc, int col_off, int bx, int by, int relu, int outbf16,
    bf16* As, bf16* Bs)
{
    const int t = threadIdx.x;
    const int w = t >> 6, lane = t & 63;
    const long brow = (long)by * 64;
    const long bcol = (long)bx * 64;
    const int wr = (w >> 1) * 32, wc = (w & 1) * 32;
    const int fr = lane & 15, half = lane >> 4;
    const int srow = t >> 3;
    const int scol = (((t & 7) ^ (srow & 7))) * 8;

    const bf16* Ag = A  + (brow + srow) * K + scol;
    const bf16* Bg = Bt + (bcol + srow) * K + scol;
    const long rowK32 = (long)32 * K;

    f32x4 acc[2][2] = {};

    for (int k0 = 0; k0 < K; k0 += 64) {
        __syncthreads();
        gload_lds16(Ag + k0,          &As[t * 8]);
        gload_lds16(Ag + k0 + rowK32, &As[2048 + t * 8]);
        gload_lds16(Bg + k0,          &Bs[t * 8]);
        gload_lds16(Bg + k0 + rowK32, &Bs[2048 + t * 8]);
        __syncthreads();
#pragma unroll
        for (int ks = 0; ks < 2; ++ks) {
            const int csw = ((ks * 4 + half) ^ (fr & 7)) * 8;
            bf16x8 af[2], bfr[2];
#pragma unroll
            for (int i = 0; i < 2; ++i)
                af[i] = *(const bf16x8*)&As[(wr + i * 16 + fr) * 64 + csw];
#pragma unroll
            for (int j = 0; j < 2; ++j)
                bfr[j] = *(const bf16x8*)&Bs[(wc + j * 16 + fr) * 64 + csw];
#pragma unroll
            for (int i = 0; i < 2; ++i)
#pragma unroll
                for (int j = 0; j < 2; ++j)
                    acc[i][j] = __builtin_amdgcn_mfma_f32_16x16x32_bf16(
                        af[i], bfr[j], acc[i][j], 0, 0, 0);
        }
    }

#pragma unroll
    for (int i = 0; i < 2; ++i) {
#pragma unroll
        for (int j = 0; j < 2; ++j) {
            const long gcol = bcol + wc + j * 16 + fr;
            const float bv = bias ? bias[gcol] : 0.0f;
#pragma unroll
            for (int v = 0; v < 4; ++v) {
                const long grow = brow + wr + i * 16 + half * 4 + v;
                float val = acc[i][j][v] + bv;
                if (relu) val = fmaxf(val, 0.0f);
                if (outbf16) ((bf16*)Cout)[grow * ldc + col_off + gcol] = (bf16)val;
                else         ((float*)Cout)[grow * ldc + col_off + gcol] = val;
            }
        }
    }
}

template<int RELU, int OUTBF16>
__global__ __launch_bounds__(256) void gemm64(
    const bf16* __restrict__ A, const bf16* __restrict__ Bt,
    const float* __restrict__ bias, void* __restrict__ Cout,
    int K, int ldc, int col_off)
{
    __shared__ bf16 As[64 * 64];
    __shared__ bf16 Bs[64 * 64];
    gemm64_body(A, Bt, bias, Cout, K, ldc, col_off,
                blockIdx.x, blockIdx.y, RELU, OUTBF16, As, Bs);
}

// ---------------------------------------------------------------------------
// mega_prep, grid (16,16,8): transposes, converts, fills, bias_comb.
// ---------------------------------------------------------------------------
__global__ __launch_bounds__(256) void mega_prep(
    const float* __restrict__ W_l, const float* __restrict__ W_r,
    const float* __restrict__ gin_W1, const float* __restrict__ fus_W,
    const float* __restrict__ gin_b2, const float* __restrict__ fus_b,
    const float* __restrict__ x, const float* __restrict__ W2,
    bf16* __restrict__ Wlrw_t, bf16* __restrict__ Wfused_t,
    bf16* __restrict__ Wfbot_t, bf16* __restrict__ W2b,
    bf16* __restrict__ xb, float* __restrict__ bias_comb,
    u32x4* __restrict__ cnt, int cnt4, u32x4* __restrict__ bm, int bm4)
{
    const int z = blockIdx.z;
    const int t = threadIdx.x;
    if (z < 5) {
        const float* s; bf16* d; int K, Nc, ldd;
        switch (z) {
            case 0: s = W_l;            d = Wlrw_t;          K = 256; Nc = 256; ldd = 256; break;
            case 1: s = W_r;            d = Wlrw_t + 65536;  K = 256; Nc = 256; ldd = 256; break;
            case 2: s = gin_W1;         d = Wlrw_t + 131072; K = 256; Nc = 256; ldd = 256; break;
            case 3: s = fus_W;          d = Wfused_t;        K = 256; Nc = 512; ldd = 512; break;
            default: s = fus_W + 256 * 512; d = Wfbot_t;     K = 256; Nc = 512; ldd = 256; break;
        }
        const int bn = blockIdx.x * 32, bk = blockIdx.y * 32;
        if (bn >= Nc || bk >= K) return;
        __shared__ float tile[32][33];
        const int tx = t & 31, ty = t >> 5;
#pragma unroll
        for (int r = 0; r < 32; r += 8)
            tile[ty + r][tx] = s[(size_t)(bk + ty + r) * Nc + bn + tx];
        __syncthreads();
#pragma unroll
        for (int r = 0; r < 32; r += 8)
            d[(size_t)(bn + ty + r) * ldd + bk + tx] = (bf16)tile[tx][ty + r];
        return;
    }
    const int bid = blockIdx.y * 16 + blockIdx.x;
    if (z == 5) {
        if (bid >= 32) return;
        const int u = bid * 256 + t;
        const float4* wv = (const float4*)W2;
        float4 a = wv[(size_t)u * 2], b = wv[(size_t)u * 2 + 1];
        bf16x8 o;
        o[0] = (bf16)a.x; o[1] = (bf16)a.y; o[2] = (bf16)a.z; o[3] = (bf16)a.w;
        o[4] = (bf16)b.x; o[5] = (bf16)b.y; o[6] = (bf16)b.z; o[7] = (bf16)b.w;
        *(bf16x8*)&W2b[(size_t)u * 8] = o;
        return;
    }
    if (z == 6) {
        const int u0 = bid * 256 + t;
        const float4* xv = (const float4*)x;
#pragma unroll
        for (int r = 0; r < 4; ++r) {
            const int u = u0 + r * 65536;
            float4 a = xv[(size_t)u * 2], b = xv[(size_t)u * 2 + 1];
            bf16x8 o;
            o[0] = (bf16)a.x; o[1] = (bf16)a.y; o[2] = (bf16)a.z; o[3] = (bf16)a.w;
            o[4] = (bf16)b.x; o[5] = (bf16)b.y; o[6] = (bf16)b.z; o[7] = (bf16)b.w;
            *(bf16x8*)&xb[(size_t)u * 8] = o;
        }
        return;
    }
    // z == 7: bias_comb + zero fills (cnt planes + bitmap)
    const int gid = bid * 256 + t;
    if (gid < 512) {
        float acc = fus_b[gid];
        for (int j = 0; j < 256; ++j)
            acc += gin_b2[j] * fus_W[(size_t)(256 + j) * 512 + gid];
        bias_comb[gid] = acc;
    }
    const int stride = 256 * 256;
    const u32x4 zv = {0u, 0u, 0u, 0u};
    for (int i = gid; i < cnt4; i += stride) cnt[i] = zv;
    for (int i = gid; i < bm4; i += stride) bm[i] = zv;
}

// ---------------------------------------------------------------------------
// Heterogeneous: xlry GEMM (1536) | Wcomb GEMM (32) | hist (512 blocks)
// (independent work merged into one launch for real overlap — stream is
//  in-order, so separate kernels strictly serialize)
// ---------------------------------------------------------------------------
__global__ __launch_bounds__(256) void hist_gemms(
    const int* __restrict__ src, const int* __restrict__ dst, int E, int N,
    int* __restrict__ cnt_dst_sh, int* __restrict__ cnt_src_sh,
    unsigned int* __restrict__ bitmap, unsigned char* __restrict__ flags,
    const bf16* __restrict__ xb, const bf16* __restrict__ Wlrw_t,
    bf16* __restrict__ xlry,
    const bf16* __restrict__ Wfbot_t, const bf16* __restrict__ W2b,
    bf16* __restrict__ Wfused_t)
{
    __shared__ bf16 As[64 * 64];
    __shared__ bf16 Bs[64 * 64];
    int bid = blockIdx.x;
    if (bid < 1536) {
        gemm64_body(xb, Wlrw_t, nullptr, xlry, 256, XLRW, 0,
                    bid % 12, bid / 12, 0, 1, As, Bs);
        return;
    }
    bid -= 1536;
    if (bid < 32) {
        gemm64_body(Wfbot_t, W2b, nullptr, Wfused_t, 256, HIDC, 256,
                    bid & 3, bid >> 2, 0, 1, As, Bs);
        return;
    }
    bid -= 32;
    const int e0 = bid * 512 + threadIdx.x;
#pragma unroll
    for (int u = 0; u < 2; ++u) {
        const int e = e0 + u * 256;
        if (e >= E) continue;
        const int sh = (e & 3) * N;
        int s = src[e], d = dst[e];
        atomicAdd(&cnt_dst_sh[sh + d], 1);
        unsigned int key  = (unsigned int)s * (unsigned int)N + (unsigned int)d;
        unsigned int word = key >> 5;
        unsigned int bit  = 1u << (key & 31u);
        unsigned int old  = atomicOr(&bitmap[word], bit);
        int own = (old & bit) == 0u;
        flags[e] = (unsigned char)own;
        if (own) atomicAdd(&cnt_src_sh[sh + s], 1);
    }
}

// ---------------------------------------------------------------------------
// Scan over sharded counts -> per-node offsets + self slots + per-(shard,
// bucket) append cursors for phase_a. Block 0 = dst dir, block 1 = src dir.
// off_dst[n] = (edges before n) + n  (self slot per node), so the edge-only
// bucket base is off_dst[32b] - 32b.
// ---------------------------------------------------------------------------
__global__ __launch_bounds__(1024) void scan_both(
    const int* __restrict__ cnt_dst_sh, int* __restrict__ off_dst,
    const int* __restrict__ cnt_src_sh, int* __restrict__ off_src,
    int* __restrict__ csr_self,
    int* __restrict__ acur_dst, int* __restrict__ acur_gin)
{
    const int self = (blockIdx.x == 0);
    const int* cnt = self ? cnt_dst_sh : cnt_src_sh;
    int* off = self ? off_dst : off_src;
    int* acur = self ? acur_dst : acur_gin;
    __shared__ int lds[1024];
    __shared__ int pshard[1024][NSH];   // per-thread (8-node) shard sums
    __shared__ int frun[1024];          // per-thread first-node offset
    const int t = threadIdx.x;
    const int base = t * 8;
    int c[8][NSH]; int tot[8]; int s = 0;
#pragma unroll
    for (int j = 0; j < 8; ++j) {
        int tt = self;
#pragma unroll
        for (int sh = 0; sh < NSH; ++sh) {
            c[j][sh] = cnt[sh * 8192 + base + j];
            tt += c[j][sh];
        }
        tot[j] = tt; s += tt;
    }
#pragma unroll
    for (int sh = 0; sh < NSH; ++sh) {
        int ps = 0;
#pragma unroll
        for (int j = 0; j < 8; ++j) ps += c[j][sh];
        pshard[t][sh] = ps;
    }
    lds[t] = s;
    __syncthreads();
    int mine = s;
    for (int o = 1; o < 1024; o <<= 1) {
        int add = (t >= o) ? lds[t - o] : 0;
        __syncthreads();
        lds[t] += add;
        __syncthreads();
    }
    int run = lds[t] - mine;
    frun[t] = run;
#pragma unroll
    for (int j = 0; j < 8; ++j) {
        off[base + j] = run;
        if (self) csr_self[run] = base + j;
        run += tot[j];
    }
    if (t == 1023) off[8192] = run;
    __syncthreads();
    if (t < NB) {
        const int b = t;                      // bucket = 32 nodes = 4 threads
        int eoff = frun[b * 4] - (self ? b * 32 : 0);
#pragma unroll
        for (int sh = 0; sh < NSH; ++sh) {
            acur[sh * NB + b] = eoff;
            eoff += pshard[b * 4][sh] + pshard[b * 4 + 1][sh] +
                    pshard[b * 4 + 2][sh] + pshard[b * 4 + 3][sh];
        }
    }
}

// ---------------------------------------------------------------------------
// phase_a: partition edges into dst-buckets (and src-buckets for GIN) via
// sharded append cursors -> dense, line-packed writes into ebuf windows.
// pack = node(13b) | lowbits(5b)<<13
// ---------------------------------------------------------------------------
__global__ __launch_bounds__(256) void phase_a(
    const int* __restrict__ src, const int* __restrict__ dst, int E,
    const unsigned char* __restrict__ flags,
    int* __restrict__ acur_dst, int* __restrict__ acur_gin,
    int* __restrict__ ebuf_dst, int* __restrict__ ebuf_gin)
{
    const int e0 = blockIdx.x * 512 + threadIdx.x;
#pragma unroll
    for (int u = 0; u < 2; ++u) {
        const int e = e0 + u * 256;
        if (e >= E) continue;
        const int sh = (e & 3) * NB;
        const int s = src[e], d = dst[e];
        const int p = atomicAdd(&acur_dst[sh + (d >> 5)], 1);
        ebuf_dst[p] = s | ((d & 31) << 13);
        if (flags[e]) {
            const int q = atomicAdd(&acur_gin[sh + (s >> 5)], 1);
            ebuf_gin[q] = d | ((s & 31) << 13);
        }
    }
}

// ---------------------------------------------------------------------------
// phase_b: one block per bucket; LDS cursors; reads its contiguous ebuf
// window, scatters into its own ~4KB csr window (single-CU, line-merged).
// Blocks 0..255 = dst buckets -> csr_src; 256..511 = src buckets -> csr_gin.
// ---------------------------------------------------------------------------
__global__ __launch_bounds__(256) void phase_b(
    const int* __restrict__ ebuf_dst, const int* __restrict__ ebuf_gin,
    const int* __restrict__ off_dst, const int* __restrict__ off_src,
    int* __restrict__ csr_src, int* __restrict__ csr_gin)
{
    __shared__ int cur[32];
    const int t = threadIdx.x;
    int b = blockIdx.x;
    if (b < NB) {
        if (t < 32) cur[t] = off_dst[b * 32 + t] + 1;   // +1: self in slot 0
        const int base = off_dst[b * 32] - b * 32;
        const int cnt  = (off_dst[(b + 1) * 32] - (b + 1) * 32) - base;
        __syncthreads();
        for (int i = t; i < cnt; i += 256) {
            const int pk = ebuf_dst[base + i];
            const int p = atomicAdd(&cur[pk >> 13], 1);
            csr_src[p] = pk & 8191;
        }
    } else {
        b -= NB;
        if (t < 32) cur[t] = off_src[b * 32 + t];
        const int base = off_src[b * 32];
        const int cnt  = off_src[(b + 1) * 32] - base;
        __syncthreads();
        for (int i = t; i < cnt; i += 256) {
            const int pk = ebuf_gin[base + i];
            const int p = atomicAdd(&cur[pk >> 13], 1);
            csr_gin[p] = pk & 8191;
        }
    }
}

// ---------------------------------------------------------------------------
// Merged GAT (blocks 0..N-1) + GIN aggregate (blocks N..2N-1).
// GAT: single-pass online softmax, pipelined x2, defer-rescale (THR=8).
// ---------------------------------------------------------------------------
__global__ __launch_bounds__(256, 8) void gatgin(
    const bf16* __restrict__ xlry, const int* __restrict__ csr_src,
    const int* __restrict__ off_dst, const float* __restrict__ att,
    const float* __restrict__ b_gat, bf16* __restrict__ cat,
    const int* __restrict__ csr_gin, const int* __restrict__ off_src,
    const float* __restrict__ gin_b1, int N)
{
    __shared__ float red[8 * 256];
    __shared__ float mslot[8][4];
    __shared__ float dslot[8][4];
    const int t = threadIdx.x;
    const int e8 = t >> 5, g = t & 31;

    if (blockIdx.x >= N) {
        const int i = blockIdx.x - N;
        const int beg = off_src[i], end = off_src[i + 1];
        const bf16* ybase = xlry + 512 + g * 8;
        float a0 = 0, a1 = 0, a2 = 0, a3 = 0, a4 = 0, a5 = 0, a6 = 0, a7 = 0;
        if (e8 == 0) {
            bf16x8 xv = *(const bf16x8*)(ybase + (size_t)i * XLRW);
            a0 = (float)xv[0]; a1 = (float)xv[1]; a2 = (float)xv[2]; a3 = (float)xv[3];
            a4 = (float)xv[4]; a5 = (float)xv[5]; a6 = (float)xv[6]; a7 = (float)xv[7];
        }
        int j = beg + e8;
        for (; j + 8 < end; j += 16) {
            const int s0 = csr_gin[j];
            const int s1 = csr_gin[j + 8];
            bf16x8 v0 = *(const bf16x8*)(ybase + (size_t)s0 * XLRW);
            bf16x8 v1 = *(const bf16x8*)(ybase + (size_t)s1 * XLRW);
            a0 += (float)v0[0] + (float)v1[0]; a1 += (float)v0[1] + (float)v1[1];
            a2 += (float)v0[2] + (float)v1[2]; a3 += (float)v0[3] + (float)v1[3];
            a4 += (float)v0[4] + (float)v1[4]; a5 += (float)v0[5] + (float)v1[5];
            a6 += (float)v0[6] + (float)v1[6]; a7 += (float)v0[7] + (float)v1[7];
        }
        if (j < end) {
            const int s = csr_gin[j];
            bf16x8 v = *(const bf16x8*)(ybase + (size_t)s * XLRW);
            a0 += (float)v[0]; a1 += (float)v[1]; a2 += (float)v[2]; a3 += (float)v[3];
            a4 += (float)v[4]; a5 += (float)v[5]; a6 += (float)v[6]; a7 += (float)v[7];
        }
        f32x4 lo = {a0, a1, a2, a3}, hi = {a4, a5, a6, a7};
        *(f32x4*)&red[e8 * 256 + g * 8]     = lo;
        *(f32x4*)&red[e8 * 256 + g * 8 + 4] = hi;
        __syncthreads();
        float acc = 0.0f;
#pragma unroll
        for (int s = 0; s < 8; ++s) acc += red[s * 256 + t];
        cat[(size_t)i * HIDC + 256 + t] = (bf16)fmaxf(acc + gin_b1[t], 0.0f);
        return;
    }

    const int d = blockIdx.x;
    const int beg = off_dst[d];
    const int cnt = off_dst[d + 1] - beg;   // includes self slot

    float xr8[8], at8[8];
    {
        bf16x8 xv = *(const bf16x8*)&xlry[(size_t)d * XLRW + 256 + g * 8];
#pragma unroll
        for (int f = 0; f < 8; ++f) xr8[f] = (float)xv[f];
        float4 q0 = *(const float4*)&att[g * 8];
        float4 q1 = *(const float4*)&att[g * 8 + 4];
        at8[0] = q0.x; at8[1] = q0.y; at8[2] = q0.z; at8[3] = q0.w;
        at8[4] = q1.x; at8[5] = q1.y; at8[6] = q1.z; at8[7] = q1.w;
    }

    const bf16* base = xlry + g * 8;
    float m = -1e30f, den = 0.0f;
    float a[8];
#pragma unroll
    for (int f = 0; f < 8; ++f) a[f] = 0.0f;

    int jj = e8;
    for (; jj + 8 < cnt; jj += 16) {
        const int s0 = csr_src[beg + jj];
        const int s1 = csr_src[beg + jj + 8];
        bf16x8 v0 = *(const bf16x8*)(base + (size_t)s0 * XLRW);
        bf16x8 v1 = *(const bf16x8*)(base + (size_t)s1 * XLRW);
        float vf0[8], vf1[8];
        float p0 = 0.0f, p1 = 0.0f;
#pragma unroll
        for (int f = 0; f < 8; ++f) {
            vf0[f] = (float)v0[f];
            vf1[f] = (float)v1[f];
            p0 += lrelu02(vf0[f] + xr8[f]) * at8[f];
            p1 += lrelu02(vf1[f] + xr8[f]) * at8[f];
        }
        p0 += __shfl_xor(p0, 1); p1 += __shfl_xor(p1, 1);
        p0 += __shfl_xor(p0, 2); p1 += __shfl_xor(p1, 2);
        p0 += __shfl_xor(p0, 4); p1 += __shfl_xor(p1, 4);
        if (!__all(p0 - m <= 8.0f)) {
            if (p0 > m) {
                const float r = __expf(m - p0);
                den *= r;
#pragma unroll
                for (int f = 0; f < 8; ++f) a[f] *= r;
                m = p0;
            }
        }
        {
            const float w = __expf(p0 - m);
            den += w;
#pragma unroll
            for (int f = 0; f < 8; ++f) a[f] = fmaf(w, vf0[f], a[f]);
        }
        if (!__all(p1 - m <= 8.0f)) {
            if (p1 > m) {
                const float r = __expf(m - p1);
                den *= r;
#pragma unroll
                for (int f = 0; f < 8; ++f) a[f] *= r;
                m = p1;
            }
        }
        {
            const float w = __expf(p1 - m);
            den += w;
#pragma unroll
            for (int f = 0; f < 8; ++f) a[f] = fmaf(w, vf1[f], a[f]);
        }
    }
    if (jj < cnt) {
        const int s = csr_src[beg + jj];
        bf16x8 v = *(const bf16x8*)(base + (size_t)s * XLRW);
        float vf[8];
        float p = 0.0f;
#pragma unroll
        for (int f = 0; f < 8; ++f) {
            vf[f] = (float)v[f];
            p += lrelu02(vf[f] + xr8[f]) * at8[f];
        }
        p += __shfl_xor(p, 1);
        p += __shfl_xor(p, 2);
        p += __shfl_xor(p, 4);
        if (!__all(p - m <= 8.0f)) {
            if (p > m) {
                const float r = __expf(m - p);
                den *= r;
#pragma unroll
                for (int f = 0; f < 8; ++f) a[f] *= r;
                m = p;
            }
        }
        const float w = __expf(p - m);
        den += w;
#pragma unroll
        for (int f = 0; f < 8; ++f) a[f] = fmaf(w, vf[f], a[f]);
    }

    {
        f32x4 lo = {a[0], a[1], a[2], a[3]}, hi = {a[4], a[5], a[6], a[7]};
        *(f32x4*)&red[e8 * 256 + g * 8]     = lo;
        *(f32x4*)&red[e8 * 256 + g * 8 + 4] = hi;
        if ((g & 7) == 0) { mslot[e8][g >> 3] = m; dslot[e8][g >> 3] = den; }
    }
    __syncthreads();

    const int h = t >> 6;
    float M = mslot[0][h];
#pragma unroll
    for (int s2 = 1; s2 < 8; ++s2) M = fmaxf(M, mslot[s2][h]);
    float accv = 0.0f, dd = 0.0f;
#pragma unroll
    for (int s2 = 0; s2 < 8; ++s2) {
        const float sc = __expf(mslot[s2][h] - M);
        accv = fmaf(sc, red[s2 * 256 + t], accv);
        dd   = fmaf(sc, dslot[s2][h], dd);
    }
    cat[(size_t)d * HIDC + t] = (bf16)(accv / dd + b_gat[t]);
}

// LayerNorm over 512 features (bf16 in, fp32 out)
__global__ __launch_bounds__(256) void layernorm512(
    const bf16* __restrict__ cbuf, const float* __restrict__ g,
    const float* __restrict__ b, float* __restrict__ out)
{
    const int r = blockIdx.x;
    const int t = threadIdx.x;
    typedef __attribute__((ext_vector_type(2))) __bf16 bf16x2;
    bf16x2 pv = *(const bf16x2*)&cbuf[(size_t)r * HIDC + t * 2];
    float v0 = (float)pv[0], v1 = (float)pv[1];
    float s = v0 + v1;
    float q = v0 * v0 + v1 * v1;
    for (int o = 1; o < 64; o <<= 1) {
        s += __shfl_xor(s, o);
        q += __shfl_xor(q, o);
    }
    __shared__ float ls[4], lq[4];
    int w = t >> 6;
    if ((t & 63) == 0) { ls[w] = s; lq[w] = q; }
    __syncthreads();
    s = ls[0] + ls[1] + ls[2] + ls[3];
    q = lq[0] + lq[1] + lq[2] + lq[3];
    float mu  = s * (1.0f / 512.0f);
    float var = q * (1.0f / 512.0f) - mu * mu;
    float rs  = rsqrtf(var + 1e-5f);
    int c0 = t * 2;
    out[(size_t)r * HIDC + c0]     = (v0 - mu) * rs * g[c0]     + b[c0];
    out[(size_t)r * HIDC + c0 + 1] = (v1 - mu) * rs * g[c0 + 1] + b[c0 + 1];
}

// ---------------------------------------------------------------------------
extern "C" void kernel_launch(void* const* d_in, const int* in_sizes, int n_in,
                              void* d_out, int out_size, void* d_ws, size_t ws_size,
                              hipStream_t stream)
{
    const float* x      = (const float*)d_in[0];
    const float* W_l    = (const float*)d_in[1];
    const float* W_r    = (const float*)d_in[2];
    const float* att    = (const float*)d_in[3];
    const float* b_gat  = (const float*)d_in[4];
    const float* gin_W1 = (const float*)d_in[5];
    const float* gin_b1 = (const float*)d_in[6];
    const float* gin_W2 = (const float*)d_in[7];
    const float* gin_b2 = (const float*)d_in[8];
    const float* fus_W  = (const float*)d_in[9];
    const float* fus_b  = (const float*)d_in[10];
    const float* ln_g   = (const float*)d_in[11];
    const float* ln_b   = (const float*)d_in[12];
    const int*   eidx   = (const int*)d_in[13];

    const int E = in_sizes[13] / 2;
    const int N = in_sizes[0] / DINC;  // 8192
    const int* src = eidx;
    const int* dst = eidx + E;

    char* ws = (char*)d_ws;
    size_t off = 0;
    auto alloc = [&](size_t bytes) -> void* {
        void* p = ws + off;
        off = (off + bytes + 255) & ~(size_t)255;
        return p;
    };
    bf16* xb       = (bf16*)alloc((size_t)N * DINC * 2);
    bf16* xlry     = (bf16*)alloc((size_t)N * XLRW * 2);
    bf16* Wlrw_t   = (bf16*)alloc((size_t)768 * 256 * 2);
    bf16* Wfused_t = (bf16*)alloc((size_t)512 * 512 * 2);
    bf16* Wfbot_t  = (bf16*)alloc((size_t)512 * 256 * 2);
    bf16* W2b      = (bf16*)alloc((size_t)256 * 256 * 2);
    bf16* cat      = (bf16*)alloc((size_t)N * HIDC * 2);
    bf16* cbuf     = (bf16*)alloc((size_t)N * HIDC * 2);
    float* bias_comb = (float*)alloc(512 * 4);
    int* cnt_dst_sh = (int*)alloc((size_t)NSH * N * 4);   // contiguous with next
    int* cnt_src_sh = (int*)alloc((size_t)NSH * N * 4);
    int* acur_dst = (int*)alloc((size_t)NSH * NB * 4);
    int* acur_gin = (int*)alloc((size_t)NSH * NB * 4);
    int* off_dst = (int*)alloc((size_t)(N + 1) * 4);
    int* off_src = (int*)alloc((size_t)(N + 1) * 4);
    int* csr_src = (int*)alloc((size_t)(E + N) * 4);   // edges + self slots
    int* csr_gin = (int*)alloc((size_t)E * 4);
    int* ebuf_dst = (int*)alloc((size_t)E * 4);
    int* ebuf_gin = (int*)alloc((size_t)E * 4);
    unsigned char* flags  = (unsigned char*)alloc((size_t)E);
    unsigned int*  bitmap = (unsigned int*)alloc((size_t)N * (size_t)N / 8);

    mega_prep<<<dim3(16, 16, 8), 256, 0, stream>>>(
        W_l, W_r, gin_W1, fus_W, gin_b2, fus_b, x, gin_W2,
        Wlrw_t, Wfused_t, Wfbot_t, W2b, xb, bias_comb,
        (u32x4*)cnt_dst_sh, (2 * NSH * N) / 4,
        (u32x4*)bitmap, (int)((size_t)N * N / 32 / 4));

    const int nh = (E + 511) / 512;
    hist_gemms<<<1536 + 32 + nh, 256, 0, stream>>>(
        src, dst, E, N, cnt_dst_sh, cnt_src_sh, bitmap, flags,
        xb, Wlrw_t, xlry, Wfbot_t, W2b, Wfused_t);

    scan_both<<<2, 1024, 0, stream>>>(cnt_dst_sh, off_dst, cnt_src_sh, off_src,
                                      csr_src, acur_dst, acur_gin);

    phase_a<<<nh, 256, 0, stream>>>(src, dst, E, flags, acur_dst, acur_gin,
                                    ebuf_dst, ebuf_gin);

    phase_b<<<2 * NB, 256, 0, stream>>>(ebuf_dst, ebuf_gin, off_dst, off_src,
                                        csr_src, csr_gin);

    gatgin<<<2 * N, 256, 0, stream>>>(xlry, csr_src, off_dst, att, b_gat, cat,
                                      csr_gin, off_src, gin_b1, N);

    gemm64<1, 1><<<dim3(8, 128), 256, 0, stream>>>(cat, Wfused_t, bias_comb, cbuf, 512, HIDC, 0);
    layernorm512<<<N, 256, 0, stream>>>(cbuf, ln_g, ln_b, (float*)d_out);

    (void)n_in; (void)out_size; (void)ws_size;
}

// Round 15
// 117.916 us; speedup vs baseline: 1.9096x; 1.9096x over previous
//
#include <hip/hip_runtime.h>

typedef __bf16 bf16;
typedef __attribute__((ext_vector_type(8))) __bf16 bf16x8;
typedef __attribute__((ext_vector_type(4))) float f32x4;
typedef __attribute__((ext_vector_type(4))) unsigned int u32x4;

#define DINC 256
#define HIDC 512
#define XLRW 768   // xlry row width: [xl(256) | xr(256) | y(256)]
#define LCAP 1024  // LDS neighbor-list chunk capacity

__device__ __forceinline__ float lrelu02(float v) { return fmaxf(v, 0.2f * v); }

__device__ __forceinline__ void gload_lds16(const void* g, void* l) {
    __builtin_amdgcn_global_load_lds(
        (const __attribute__((address_space(1))) unsigned int*)g,
        (__attribute__((address_space(3))) unsigned int*)l, 16, 0, 0);
}

// ---------------------------------------------------------------------------
// 64x64 tile BK=64 bf16 MFMA GEMM body, bank-conflict-free via XOR swizzle.
// ---------------------------------------------------------------------------
__device__ __forceinline__ void gemm64_body(
    const bf16* __restrict__ A, const bf16* __restrict__ Bt,
    const float* __restrict__ bias, void* __restrict__ Cout,
    int K, int ldc, int col_off, int bx, int by, int relu, int outbf16,
    bf16* As, bf16* Bs)
{
    const int t = threadIdx.x;
    const int w = t >> 6, lane = t & 63;
    const long brow = (long)by * 64;
    const long bcol = (long)bx * 64;
    const int wr = (w >> 1) * 32, wc = (w & 1) * 32;
    const int fr = lane & 15, half = lane >> 4;
    const int srow = t >> 3;
    const int scol = (((t & 7) ^ (srow & 7))) * 8;

    const bf16* Ag = A  + (brow + srow) * K + scol;
    const bf16* Bg = Bt + (bcol + srow) * K + scol;
    const long rowK32 = (long)32 * K;

    f32x4 acc[2][2] = {};

    for (int k0 = 0; k0 < K; k0 += 64) {
        __syncthreads();
        gload_lds16(Ag + k0,          &As[t * 8]);
        gload_lds16(Ag + k0 + rowK32, &As[2048 + t * 8]);
        gload_lds16(Bg + k0,          &Bs[t * 8]);
        gload_lds16(Bg + k0 + rowK32, &Bs[2048 + t * 8]);
        __syncthreads();
#pragma unroll
        for (int ks = 0; ks < 2; ++ks) {
            const int csw = ((ks * 4 + half) ^ (fr & 7)) * 8;
            bf16x8 af[2], bfr[2];
#pragma unroll
            for (int i = 0; i < 2; ++i)
                af[i] = *(const bf16x8*)&As[(wr + i * 16 + fr) * 64 + csw];
#pragma unroll
            for (int j = 0; j < 2; ++j)
                bfr[j] = *(const bf16x8*)&Bs[(wc + j * 16 + fr) * 64 + csw];
#pragma unroll
            for (int i = 0; i < 2; ++i)
#pragma unroll
                for (int j = 0; j < 2; ++j)
                    acc[i][j] = __builtin_amdgcn_mfma_f32_16x16x32_bf16(
                        af[i], bfr[j], acc[i][j], 0, 0, 0);
        }
    }

#pragma unroll
    for (int i = 0; i < 2; ++i) {
#pragma unroll
        for (int j = 0; j < 2; ++j) {
            const long gcol = bcol + wc + j * 16 + fr;
            const float bv = bias ? bias[gcol] : 0.0f;
#pragma unroll
            for (int v = 0; v < 4; ++v) {
                const long grow = brow + wr + i * 16 + half * 4 + v;
                float val = acc[i][j][v] + bv;
                if (relu) val = fmaxf(val, 0.0f);
                if (outbf16) ((bf16*)Cout)[grow * ldc + col_off + gcol] = (bf16)val;
                else         ((float*)Cout)[grow * ldc + col_off + gcol] = val;
            }
        }
    }
}

template<int RELU, int OUTBF16>
__global__ __launch_bounds__(256) void gemm64(
    const bf16* __restrict__ A, const bf16* __restrict__ Bt,
    const float* __restrict__ bias, void* __restrict__ Cout,
    int K, int ldc, int col_off)
{
    __shared__ bf16 As[64 * 64];
    __shared__ bf16 Bs[64 * 64];
    gemm64_body(A, Bt, bias, Cout, K, ldc, col_off,
                blockIdx.x, blockIdx.y, RELU, OUTBF16, As, Bs);
}

// ---------------------------------------------------------------------------
// mega_prep, grid (16,16,8): transposes, converts, fills, bias_comb.
// ---------------------------------------------------------------------------
__global__ __launch_bounds__(256) void mega_prep(
    const float* __restrict__ W_l, const float* __restrict__ W_r,
    const float* __restrict__ gin_W1, const float* __restrict__ fus_W,
    const float* __restrict__ gin_b2, const float* __restrict__ fus_b,
    const float* __restrict__ x, const float* __restrict__ W2,
    bf16* __restrict__ Wlrw_t, bf16* __restrict__ Wfused_t,
    bf16* __restrict__ Wfbot_t, bf16* __restrict__ W2b,
    bf16* __restrict__ xb, float* __restrict__ bias_comb,
    u32x4* __restrict__ cnt, int cnt4, u32x4* __restrict__ bm, int bm4)
{
    const int z = blockIdx.z;
    const int t = threadIdx.x;
    if (z < 5) {
        const float* s; bf16* d; int K, Nc, ldd;
        switch (z) {
            case 0: s = W_l;            d = Wlrw_t;          K = 256; Nc = 256; ldd = 256; break;
            case 1: s = W_r;            d = Wlrw_t + 65536;  K = 256; Nc = 256; ldd = 256; break;
            case 2: s = gin_W1;         d = Wlrw_t + 131072; K = 256; Nc = 256; ldd = 256; break;
            case 3: s = fus_W;          d = Wfused_t;        K = 256; Nc = 512; ldd = 512; break;
            default: s = fus_W + 256 * 512; d = Wfbot_t;     K = 256; Nc = 512; ldd = 256; break;
        }
        const int bn = blockIdx.x * 32, bk = blockIdx.y * 32;
        if (bn >= Nc || bk >= K) return;
        __shared__ float tile[32][33];
        const int tx = t & 31, ty = t >> 5;
#pragma unroll
        for (int r = 0; r < 32; r += 8)
            tile[ty + r][tx] = s[(size_t)(bk + ty + r) * Nc + bn + tx];
        __syncthreads();
#pragma unroll
        for (int r = 0; r < 32; r += 8)
            d[(size_t)(bn + ty + r) * ldd + bk + tx] = (bf16)tile[tx][ty + r];
        return;
    }
    const int bid = blockIdx.y * 16 + blockIdx.x;
    if (z == 5) {
        if (bid >= 32) return;
        const int u = bid * 256 + t;
        const float4* wv = (const float4*)W2;
        float4 a = wv[(size_t)u * 2], b = wv[(size_t)u * 2 + 1];
        bf16x8 o;
        o[0] = (bf16)a.x; o[1] = (bf16)a.y; o[2] = (bf16)a.z; o[3] = (bf16)a.w;
        o[4] = (bf16)b.x; o[5] = (bf16)b.y; o[6] = (bf16)b.z; o[7] = (bf16)b.w;
        *(bf16x8*)&W2b[(size_t)u * 8] = o;
        return;
    }
    if (z == 6) {
        const int u0 = bid * 256 + t;
        const float4* xv = (const float4*)x;
#pragma unroll
        for (int r = 0; r < 4; ++r) {
            const int u = u0 + r * 65536;
            float4 a = xv[(size_t)u * 2], b = xv[(size_t)u * 2 + 1];
            bf16x8 o;
            o[0] = (bf16)a.x; o[1] = (bf16)a.y; o[2] = (bf16)a.z; o[3] = (bf16)a.w;
            o[4] = (bf16)b.x; o[5] = (bf16)b.y; o[6] = (bf16)b.z; o[7] = (bf16)b.w;
            *(bf16x8*)&xb[(size_t)u * 8] = o;
        }
        return;
    }
    // z == 7: bias_comb + zero fills (dupcnt+dup_n region, 2 bitmaps)
    const int gid = bid * 256 + t;
    if (gid < 512) {
        float acc = fus_b[gid];
        for (int j = 0; j < 256; ++j)
            acc += gin_b2[j] * fus_W[(size_t)(256 + j) * 512 + gid];
        bias_comb[gid] = acc;
    }
    const int stride = 256 * 256;
    const u32x4 zv = {0u, 0u, 0u, 0u};
    for (int i = gid; i < cnt4; i += stride) cnt[i] = zv;
    for (int i = gid; i < bm4; i += stride) bm[i] = zv;
}

// ---------------------------------------------------------------------------
// Heterogeneous: xlry GEMM (1536) | Wcomb GEMM (32) | edge pass (512 blocks):
// set bitmap[s*N+d] (GIN rows) and bitmapT[d*N+s] (GAT rows); duplicates
// (atomicOr return had bit set) appended to dup_pair + per-dst count.
// ---------------------------------------------------------------------------
__global__ __launch_bounds__(256) void edges_gemms(
    const int* __restrict__ src, const int* __restrict__ dst, int E, int N,
    unsigned int* __restrict__ bitmap, unsigned int* __restrict__ bitmapT,
    int* __restrict__ dupcnt, int* __restrict__ dup_n, int* __restrict__ dup_pair,
    const bf16* __restrict__ xb, const bf16* __restrict__ Wlrw_t,
    bf16* __restrict__ xlry,
    const bf16* __restrict__ Wfbot_t, const bf16* __restrict__ W2b,
    bf16* __restrict__ Wfused_t)
{
    __shared__ bf16 As[64 * 64];
    __shared__ bf16 Bs[64 * 64];
    int bid = blockIdx.x;
    if (bid < 1536) {
        gemm64_body(xb, Wlrw_t, nullptr, xlry, 256, XLRW, 0,
                    bid % 12, bid / 12, 0, 1, As, Bs);
        return;
    }
    bid -= 1536;
    if (bid < 32) {
        gemm64_body(Wfbot_t, W2b, nullptr, Wfused_t, 256, HIDC, 256,
                    bid & 3, bid >> 2, 0, 1, As, Bs);
        return;
    }
    bid -= 32;
    const int e0 = bid * 512 + threadIdx.x;
#pragma unroll
    for (int u = 0; u < 2; ++u) {
        const int e = e0 + u * 256;
        if (e >= E) continue;
        const int s = src[e], d = dst[e];
        const unsigned int keyT = (unsigned int)d * (unsigned int)N + (unsigned int)s;
        const unsigned int bitT = 1u << (keyT & 31u);
        const unsigned int oldT = atomicOr(&bitmapT[keyT >> 5], bitT);
        const unsigned int keyS = (unsigned int)s * (unsigned int)N + (unsigned int)d;
        atomicOr(&bitmap[keyS >> 5], 1u << (keyS & 31u));
        if (oldT & bitT) {                       // duplicate instance
            const int p = atomicAdd(dup_n, 1);
            dup_pair[p] = (d << 13) | s;
            atomicAdd(&dupcnt[d], 1);
        }
    }
}

// ---------------------------------------------------------------------------
// dup_prep (1 block, 1024 thr): scan dupcnt -> dup_off, scatter dup_pair -> dup_s
// ---------------------------------------------------------------------------
__global__ __launch_bounds__(1024) void dup_prep(
    int* __restrict__ dupcnt, int* __restrict__ dup_off,
    const int* __restrict__ dup_pair, const int* __restrict__ dup_n,
    int* __restrict__ dup_s)
{
    __shared__ int lds[1024];
    const int t = threadIdx.x;
    const int base = t * 8;
    int v[8]; int s = 0;
#pragma unroll
    for (int j = 0; j < 8; ++j) { v[j] = dupcnt[base + j]; s += v[j]; }
    lds[t] = s;
    __syncthreads();
    int mine = s;
    for (int o = 1; o < 1024; o <<= 1) {
        int add = (t >= o) ? lds[t - o] : 0;
        __syncthreads();
        lds[t] += add;
        __syncthreads();
    }
    int run = lds[t] - mine;
#pragma unroll
    for (int j = 0; j < 8; ++j) {
        dup_off[base + j] = run;
        dupcnt[base + j] = run;      // reuse as scatter cursor
        run += v[j];
    }
    if (t == 1023) dup_off[8192] = run;
    __syncthreads();
    const int n = *dup_n;
    for (int i = t; i < n; i += 1024) {
        const int pk = dup_pair[i];
        const int d = pk >> 13;
        const int p = atomicAdd(&dupcnt[d], 1);
        dup_s[p] = pk & 8191;
    }
}

// ---------------------------------------------------------------------------
// Merged GAT (blocks 0..N-1) + GIN (blocks N..2N-1), bitmap-row driven.
// Per node: load its 256-word bitmap row into LDS, chunk-extract set bits
// into an LDS list, run the online-softmax (GAT) / sum (GIN) over the list.
// GAT appends duplicate instances + the self-loop as a final chunk.
// ---------------------------------------------------------------------------
__global__ __launch_bounds__(256, 8) void gatgin(
    const bf16* __restrict__ xlry,
    const unsigned int* __restrict__ bitmap, const unsigned int* __restrict__ bitmapT,
    const int* __restrict__ dup_off, const int* __restrict__ dup_s,
    const float* __restrict__ att, const float* __restrict__ b_gat,
    bf16* __restrict__ cat, const float* __restrict__ gin_b1, int N)
{
    __shared__ __align__(16) char lraw[8 * 256 * 4];   // list (4KB) then red (8KB)
    __shared__ unsigned int wordbuf[256];
    __shared__ float mslot[8][4];
    __shared__ float dslot[8][4];
    __shared__ int lcnt;
    int* list = (int*)lraw;
    float* red = (float*)lraw;
    const int t = threadIdx.x;
    const int e8 = t >> 5, g = t & 31;

    if (blockIdx.x >= N) {
        // ---------------- GIN: sum y over bitmap row i + self ----------------
        const int i = blockIdx.x - N;
        wordbuf[t] = bitmap[(size_t)i * 256 + t];
        const bf16* ybase = xlry + 512 + g * 8;
        float a0 = 0, a1 = 0, a2 = 0, a3 = 0, a4 = 0, a5 = 0, a6 = 0, a7 = 0;
        if (e8 == 0) {
            bf16x8 xv = *(const bf16x8*)(ybase + (size_t)i * XLRW);
            a0 = (float)xv[0]; a1 = (float)xv[1]; a2 = (float)xv[2]; a3 = (float)xv[3];
            a4 = (float)xv[4]; a5 = (float)xv[5]; a6 = (float)xv[6]; a7 = (float)xv[7];
        }
        for (;;) {
            if (t == 0) lcnt = 0;
            __syncthreads();
            unsigned int w = wordbuf[t];
            while (w) {
                const int p = atomicAdd(&lcnt, 1);
                if (p >= LCAP) break;
                const int b = __ffs(w) - 1;
                w &= w - 1;
                list[p] = t * 32 + b;
            }
            wordbuf[t] = w;
            __syncthreads();
            const int n2 = min(lcnt, LCAP);
            if (n2 == 0) break;
            int j = e8;
            for (; j + 8 < n2; j += 16) {
                const int s0 = list[j], s1 = list[j + 8];
                bf16x8 v0 = *(const bf16x8*)(ybase + (size_t)s0 * XLRW);
                bf16x8 v1 = *(const bf16x8*)(ybase + (size_t)s1 * XLRW);
                a0 += (float)v0[0] + (float)v1[0]; a1 += (float)v0[1] + (float)v1[1];
                a2 += (float)v0[2] + (float)v1[2]; a3 += (float)v0[3] + (float)v1[3];
                a4 += (float)v0[4] + (float)v1[4]; a5 += (float)v0[5] + (float)v1[5];
                a6 += (float)v0[6] + (float)v1[6]; a7 += (float)v0[7] + (float)v1[7];
            }
            if (j < n2) {
                const int s = list[j];
                bf16x8 v = *(const bf16x8*)(ybase + (size_t)s * XLRW);
                a0 += (float)v[0]; a1 += (float)v[1]; a2 += (float)v[2]; a3 += (float)v[3];
                a4 += (float)v[4]; a5 += (float)v[5]; a6 += (float)v[6]; a7 += (float)v[7];
            }
            __syncthreads();
            if (n2 < LCAP) break;
        }
        f32x4 lo = {a0, a1, a2, a3}, hi = {a4, a5, a6, a7};
        *(f32x4*)&red[e8 * 256 + g * 8]     = lo;
        *(f32x4*)&red[e8 * 256 + g * 8 + 4] = hi;
        __syncthreads();
        float acc = 0.0f;
#pragma unroll
        for (int s = 0; s < 8; ++s) acc += red[s * 256 + t];
        cat[(size_t)i * HIDC + 256 + t] = (bf16)fmaxf(acc + gin_b1[t], 0.0f);
        return;
    }

    // ---------------- GAT: online softmax over bitmapT row d + dups + self --
    const int d = blockIdx.x;
    wordbuf[t] = bitmapT[(size_t)d * 256 + t];

    float xr8[8], at8[8];
    {
        bf16x8 xv = *(const bf16x8*)&xlry[(size_t)d * XLRW + 256 + g * 8];
#pragma unroll
        for (int f = 0; f < 8; ++f) xr8[f] = (float)xv[f];
        float4 q0 = *(const float4*)&att[g * 8];
        float4 q1 = *(const float4*)&att[g * 8 + 4];
        at8[0] = q0.x; at8[1] = q0.y; at8[2] = q0.z; at8[3] = q0.w;
        at8[4] = q1.x; at8[5] = q1.y; at8[6] = q1.z; at8[7] = q1.w;
    }
    const bf16* base = xlry + g * 8;
    float m = -1e30f, den = 0.0f;
    float a[8];
#pragma unroll
    for (int f = 0; f < 8; ++f) a[f] = 0.0f;

    auto process = [&](int n2) {
        int jj = e8;
        for (; jj + 8 < n2; jj += 16) {
            const int s0 = list[jj], s1 = list[jj + 8];
            bf16x8 v0 = *(const bf16x8*)(base + (size_t)s0 * XLRW);
            bf16x8 v1 = *(const bf16x8*)(base + (size_t)s1 * XLRW);
            float vf0[8], vf1[8];
            float p0 = 0.0f, p1 = 0.0f;
#pragma unroll
            for (int f = 0; f < 8; ++f) {
                vf0[f] = (float)v0[f];
                vf1[f] = (float)v1[f];
                p0 += lrelu02(vf0[f] + xr8[f]) * at8[f];
                p1 += lrelu02(vf1[f] + xr8[f]) * at8[f];
            }
            p0 += __shfl_xor(p0, 1); p1 += __shfl_xor(p1, 1);
            p0 += __shfl_xor(p0, 2); p1 += __shfl_xor(p1, 2);
            p0 += __shfl_xor(p0, 4); p1 += __shfl_xor(p1, 4);
            if (!__all(p0 - m <= 8.0f)) {
                if (p0 > m) {
                    const float r = __expf(m - p0);
                    den *= r;
#pragma unroll
                    for (int f = 0; f < 8; ++f) a[f] *= r;
                    m = p0;
                }
            }
            {
                const float w2 = __expf(p0 - m);
                den += w2;
#pragma unroll
                for (int f = 0; f < 8; ++f) a[f] = fmaf(w2, vf0[f], a[f]);
            }
            if (!__all(p1 - m <= 8.0f)) {
                if (p1 > m) {
                    const float r = __expf(m - p1);
                    den *= r;
#pragma unroll
                    for (int f = 0; f < 8; ++f) a[f] *= r;
                    m = p1;
                }
            }
            {
                const float w2 = __expf(p1 - m);
                den += w2;
#pragma unroll
                for (int f = 0; f < 8; ++f) a[f] = fmaf(w2, vf1[f], a[f]);
            }
        }
        if (jj < n2) {
            const int s = list[jj];
            bf16x8 v = *(const bf16x8*)(base + (size_t)s * XLRW);
            float vf[8];
            float p = 0.0f;
#pragma unroll
            for (int f = 0; f < 8; ++f) {
                vf[f] = (float)v[f];
                p += lrelu02(vf[f] + xr8[f]) * at8[f];
            }
            p += __shfl_xor(p, 1);
            p += __shfl_xor(p, 2);
            p += __shfl_xor(p, 4);
            if (!__all(p - m <= 8.0f)) {
                if (p > m) {
                    const float r = __expf(m - p);
                    den *= r;
#pragma unroll
                    for (int f = 0; f < 8; ++f) a[f] *= r;
                    m = p;
                }
            }
            const float w2 = __expf(p - m);
            den += w2;
#pragma unroll
            for (int f = 0; f < 8; ++f) a[f] = fmaf(w2, vf[f], a[f]);
        }
    };

    for (;;) {
        if (t == 0) lcnt = 0;
        __syncthreads();
        unsigned int w = wordbuf[t];
        while (w) {
            const int p = atomicAdd(&lcnt, 1);
            if (p >= LCAP) break;
            const int b = __ffs(w) - 1;
            w &= w - 1;
            list[p] = t * 32 + b;
        }
        wordbuf[t] = w;
        __syncthreads();
        const int n2 = min(lcnt, LCAP);
        if (n2 == 0) break;
        process(n2);
        __syncthreads();
        if (n2 < LCAP) break;
    }

    // dups + self-loop as final chunk(s)
    const int db = dup_off[d];
    const int ndup = dup_off[d + 1] - db;
    int rem = ndup + 1, pos = 0;
    while (rem > 0) {
        const int take = min(rem, LCAP);
        __syncthreads();
        if (t < take) list[t] = (pos + t < ndup) ? dup_s[db + pos + t] : d;
        __syncthreads();
        process(take);
        pos += take; rem -= take;
    }
    __syncthreads();

    {
        f32x4 lo = {a[0], a[1], a[2], a[3]}, hi = {a[4], a[5], a[6], a[7]};
        *(f32x4*)&red[e8 * 256 + g * 8]     = lo;
        *(f32x4*)&red[e8 * 256 + g * 8 + 4] = hi;
        if ((g & 7) == 0) { mslot[e8][g >> 3] = m; dslot[e8][g >> 3] = den; }
    }
    __syncthreads();

    const int h = t >> 6;
    float M = mslot[0][h];
#pragma unroll
    for (int s2 = 1; s2 < 8; ++s2) M = fmaxf(M, mslot[s2][h]);
    float accv = 0.0f, dd = 0.0f;
#pragma unroll
    for (int s2 = 0; s2 < 8; ++s2) {
        const float sc = __expf(mslot[s2][h] - M);
        accv = fmaf(sc, red[s2 * 256 + t], accv);
        dd   = fmaf(sc, dslot[s2][h], dd);
    }
    cat[(size_t)d * HIDC + t] = (bf16)(accv / dd + b_gat[t]);
}

// LayerNorm over 512 features (bf16 in, fp32 out)
__global__ __launch_bounds__(256) void layernorm512(
    const bf16* __restrict__ cbuf, const float* __restrict__ g,
    const float* __restrict__ b, float* __restrict__ out)
{
    const int r = blockIdx.x;
    const int t = threadIdx.x;
    typedef __attribute__((ext_vector_type(2))) __bf16 bf16x2;
    bf16x2 pv = *(const bf16x2*)&cbuf[(size_t)r * HIDC + t * 2];
    float v0 = (float)pv[0], v1 = (float)pv[1];
    float s = v0 + v1;
    float q = v0 * v0 + v1 * v1;
    for (int o = 1; o < 64; o <<= 1) {
        s += __shfl_xor(s, o);
        q += __shfl_xor(q, o);
    }
    __shared__ float ls[4], lq[4];
    int w = t >> 6;
    if ((t & 63) == 0) { ls[w] = s; lq[w] = q; }
    __syncthreads();
    s = ls[0] + ls[1] + ls[2] + ls[3];
    q = lq[0] + lq[1] + lq[2] + lq[3];
    float mu  = s * (1.0f / 512.0f);
    float var = q * (1.0f / 512.0f) - mu * mu;
    float rs  = rsqrtf(var + 1e-5f);
    int c0 = t * 2;
    out[(size_t)r * HIDC + c0]     = (v0 - mu) * rs * g[c0]     + b[c0];
    out[(size_t)r * HIDC + c0 + 1] = (v1 - mu) * rs * g[c0 + 1] + b[c0 + 1];
}

// ---------------------------------------------------------------------------
extern "C" void kernel_launch(void* const* d_in, const int* in_sizes, int n_in,
                              void* d_out, int out_size, void* d_ws, size_t ws_size,
                              hipStream_t stream)
{
    const float* x      = (const float*)d_in[0];
    const float* W_l    = (const float*)d_in[1];
    const float* W_r    = (const float*)d_in[2];
    const float* att    = (const float*)d_in[3];
    const float* b_gat  = (const float*)d_in[4];
    const float* gin_W1 = (const float*)d_in[5];
    const float* gin_b1 = (const float*)d_in[6];
    const float* gin_W2 = (const float*)d_in[7];
    const float* gin_b2 = (const float*)d_in[8];
    const float* fus_W  = (const float*)d_in[9];
    const float* fus_b  = (const float*)d_in[10];
    const float* ln_g   = (const float*)d_in[11];
    const float* ln_b   = (const float*)d_in[12];
    const int*   eidx   = (const int*)d_in[13];

    const int E = in_sizes[13] / 2;
    const int N = in_sizes[0] / DINC;  // 8192
    const int* src = eidx;
    const int* dst = eidx + E;

    char* ws = (char*)d_ws;
    size_t off = 0;
    auto alloc = [&](size_t bytes) -> void* {
        void* p = ws + off;
        off = (off + bytes + 255) & ~(size_t)255;
        return p;
    };
    bf16* xb       = (bf16*)alloc((size_t)N * DINC * 2);
    bf16* xlry     = (bf16*)alloc((size_t)N * XLRW * 2);
    bf16* Wlrw_t   = (bf16*)alloc((size_t)768 * 256 * 2);
    bf16* Wfused_t = (bf16*)alloc((size_t)512 * 512 * 2);
    bf16* Wfbot_t  = (bf16*)alloc((size_t)512 * 256 * 2);
    bf16* W2b      = (bf16*)alloc((size_t)256 * 256 * 2);
    bf16* cat      = (bf16*)alloc((size_t)N * HIDC * 2);
    bf16* cbuf     = (bf16*)alloc((size_t)N * HIDC * 2);
    float* bias_comb = (float*)alloc(512 * 4);
    int* dupcnt  = (int*)alloc((size_t)N * 4);          // + dup_n contiguous
    int* dup_n   = (int*)alloc(4);
    int* dup_off = (int*)alloc((size_t)(N + 1) * 4);
    int* dup_pair = (int*)alloc((size_t)E * 4);
    int* dup_s    = (int*)alloc((size_t)E * 4);
    unsigned int* bitmap  = (unsigned int*)alloc((size_t)N * (size_t)N / 8);
    unsigned int* bitmapT = (unsigned int*)alloc((size_t)N * (size_t)N / 8);

    mega_prep<<<dim3(16, 16, 8), 256, 0, stream>>>(
        W_l, W_r, gin_W1, fus_W, gin_b2, fus_b, x, gin_W2,
        Wlrw_t, Wfused_t, Wfbot_t, W2b, xb, bias_comb,
        (u32x4*)dupcnt, (N + 256) / 4,                       // covers dupcnt+dup_n
        (u32x4*)bitmap, (int)(2 * ((size_t)N * N / 32) / 4)); // both bitmaps (contiguous)

    const int nh = (E + 511) / 512;
    edges_gemms<<<1536 + 32 + nh, 256, 0, stream>>>(
        src, dst, E, N, bitmap, bitmapT, dupcnt, dup_n, dup_pair,
        xb, Wlrw_t, xlry, Wfbot_t, W2b, Wfused_t);

    dup_prep<<<1, 1024, 0, stream>>>(dupcnt, dup_off, dup_pair, dup_n, dup_s);

    gatgin<<<2 * N, 256, 0, stream>>>(xlry, bitmap, bitmapT, dup_off, dup_s,
                                      att, b_gat, cat, gin_b1, N);

    gemm64<1, 1><<<dim3(8, 128), 256, 0, stream>>>(cat, Wfused_t, bias_comb, cbuf, 512, HIDC, 0);
    layernorm512<<<N, 256, 0, stream>>>(cbuf, ln_g, ln_b, (float*)d_out);

    (void)n_in; (void)out_size; (void)ws_size;
}